// Round 14
// baseline (144.209 us; speedup 1.0000x reference)
//
#include <hip/hip_runtime.h>
#include <hip/hip_bf16.h>

#define N_ 16
#define D_ 2048
#define H_ 32
#define W_ 32
#define HW_ 1024
#define F_ 512

typedef unsigned short u16;
typedef unsigned int u32;
typedef __attribute__((ext_vector_type(8))) short bf16x8;
typedef __attribute__((ext_vector_type(4))) float f32x4;

__device__ __forceinline__ u16 f2bf(float f) {
  union { float fv; u32 u; } c; c.fv = f;
  u32 u = c.u;
  u32 r = (u + 0x7fffu + ((u >> 16) & 1u)) >> 16;   // RNE
  return (u16)r;
}

#define GLD_LDS16(gp, lp) __builtin_amdgcn_global_load_lds( \
    (const __attribute__((address_space(1))) void*)(gp), \
    (__attribute__((address_space(3))) void*)(lp), 16, 0, 0)

// ---- K0: zero sumsq+gbuf (192 KB contiguous) ----
__global__ __launch_bounds__(256) void k_zero(float* __restrict__ p) {
  int i = blockIdx.x * 256 + threadIdx.x;
  ((float4*)p)[i] = (float4){0.f, 0.f, 0.f, 0.f};
}

// ---- K1: sum of squares over channel dim -> sumsq[n][hw] (atomic partials) ----
__global__ __launch_bounds__(256) void k_sumsq(const float* __restrict__ x, float* __restrict__ sumsq) {
  const int n = blockIdx.x;        // 16
  const int dc = blockIdx.y;       // 32 chunks x 64 d
  const int t = threadIdx.x;
  const float* xp = x + ((size_t)n * D_ + (size_t)dc * 64) * HW_;
  float s0 = 0.f, s1 = 0.f, s2 = 0.f, s3 = 0.f;
  for (int d = 0; d < 64; ++d) {
    const float* row = xp + (size_t)d * HW_;
    float v0 = row[t], v1 = row[t + 256], v2 = row[t + 512], v3 = row[t + 768];
    s0 += v0 * v0; s1 += v1 * v1; s2 += v2 * v2; s3 += v3 * v3;
  }
  atomicAdd(&sumsq[n * HW_ + t      ], s0);
  atomicAdd(&sumsq[n * HW_ + t + 256], s1);
  atomicAdd(&sumsq[n * HW_ + t + 512], s2);
  atomicAdd(&sumsq[n * HW_ + t + 768], s3);
}

// ---- K2: float4-vectorized separable 3x3 box + GeM partials (r13 form) ----
__global__ __launch_bounds__(256) void k_box2(const float* __restrict__ x,
    const float* __restrict__ sumsq, const float* __restrict__ pvec,
    float* __restrict__ gbuf, u16* __restrict__ packA) {
  const int n = blockIdx.x, ht = blockIdx.y, dc = blockIdx.z;
  const int h0 = ht * 4, d0 = dc * 64;
  const int t = threadIdx.x;
  const int w4 = t & 7, dg = t >> 3;
  const int wq = w4 * 4;
  const float p = pvec[0];
  const bool p3 = (p == 3.0f);

  __shared__ __align__(16) u16 sbox[128 * 68];   // [hw 128][d 64 pad->68]
  __shared__ __align__(16) float rnl[6][32];

  if (t < 192) {
    int jj = t >> 5, w = t & 31;
    int hp = h0 - 1 + jj;
    float r = 0.f;
    if (hp >= 0 && hp < H_) r = 1.0f / fmaxf(sqrtf(sumsq[n * HW_ + hp * W_ + w]), 1e-12f);
    rnl[jj][w] = r;
  }
  __syncthreads();

  float s0 = 0.f, s1 = 0.f;
  #pragma unroll
  for (int dj = 0; dj < 2; ++dj) {
    const int d = d0 + dg * 2 + dj;
    const float* base = x + ((size_t)(n * D_ + d)) * HW_ + wq;
    float4 v[6];
    #pragma unroll
    for (int jj = 0; jj < 6; ++jj) {
      int hp = h0 - 1 + jj;
      if (hp >= 0 && hp < H_) {
        float4 xv = *(const float4*)(base + hp * W_);
        float4 rr = *(const float4*)(&rnl[jj][wq]);
        v[jj].x = xv.x * rr.x; v[jj].y = xv.y * rr.y;
        v[jj].z = xv.z * rr.z; v[jj].w = xv.w * rr.w;
      } else {
        v[jj] = (float4){0.f, 0.f, 0.f, 0.f};
      }
    }
    float g = 0.f;
    #pragma unroll
    for (int jj = 1; jj <= 4; ++jj) {
      float cx = fmaxf(v[jj].x, 1e-6f), cy = fmaxf(v[jj].y, 1e-6f);
      float cz = fmaxf(v[jj].z, 1e-6f), cw = fmaxf(v[jj].w, 1e-6f);
      if (p3) g += cx * cx * cx + cy * cy * cy + cz * cz * cz + cw * cw * cw;
      else    g += __powf(cx, p) + __powf(cy, p) + __powf(cz, p) + __powf(cw, p);
    }
    if (dj == 0) s0 = g; else s1 = g;
    #pragma unroll
    for (int jj = 0; jj < 6; ++jj) {
      float lf = __shfl_up(v[jj].w, 1, 8);
      float rf = __shfl_down(v[jj].x, 1, 8);
      if (w4 == 0) lf = 0.f;
      if (w4 == 7) rf = 0.f;
      float4 h;
      h.x = lf + v[jj].x + v[jj].y;
      h.y = v[jj].x + v[jj].y + v[jj].z;
      h.z = v[jj].y + v[jj].z + v[jj].w;
      h.w = v[jj].z + v[jj].w + rf;
      v[jj] = h;
    }
    #pragma unroll
    for (int k = 0; k < 4; ++k) {
      float4 b;
      b.x = v[k].x + v[k + 1].x + v[k + 2].x;
      b.y = v[k].y + v[k + 1].y + v[k + 2].y;
      b.z = v[k].z + v[k + 1].z + v[k + 2].z;
      b.w = v[k].w + v[k + 1].w + v[k + 2].w;
      const int rb = k * 32 + wq;
      sbox[(rb + 0) * 68 + dg * 2 + dj] = f2bf(b.x);
      sbox[(rb + 1) * 68 + dg * 2 + dj] = f2bf(b.y);
      sbox[(rb + 2) * 68 + dg * 2 + dj] = f2bf(b.z);
      sbox[(rb + 3) * 68 + dg * 2 + dj] = f2bf(b.w);
    }
  }
  __syncthreads();

  {
    const int r = t >> 1, half = t & 1;
    const u16* srcp = sbox + r * 68 + half * 32;
    uint2 a[8];
    #pragma unroll
    for (int q = 0; q < 8; ++q) a[q] = *(const uint2*)(srcp + q * 4);
    const int mt = n * 16 + ht * 2 + (r >> 6);
    const int mf = (r >> 4) & 3, r15 = r & 15;
    const int kt = dc * 2 + half;
    u16* dst = packA + ((size_t)(mt * 64 + kt) * 4 + mf) * 512 + r15 * 8;
    #pragma unroll
    for (int q = 0; q < 4; ++q) {        // q = hi
      uint4 b;
      b.x = a[2 * q].x; b.y = a[2 * q].y; b.z = a[2 * q + 1].x; b.w = a[2 * q + 1].y;
      *(uint4*)(dst + q * 128) = b;
    }
  }

  {
    float v0 = s0, v1 = s1;
    v0 += __shfl_xor(v0, 1, 8); v1 += __shfl_xor(v1, 1, 8);
    v0 += __shfl_xor(v0, 2, 8); v1 += __shfl_xor(v1, 2, 8);
    v0 += __shfl_xor(v0, 4, 8); v1 += __shfl_xor(v1, 4, 8);
    if (w4 == 0) {
      atomicAdd(&gbuf[n * D_ + d0 + dg * 2    ], v0);
      atomicAdd(&gbuf[n * D_ + d0 + dg * 2 + 1], v1);
    }
  }
}

// ---- K3: proj_w fp32 -> bf16, fragment-packed: packB[wq][kt][nf][lane][8] ----
__global__ __launch_bounds__(256) void k_wconv(const float* __restrict__ w, u16* __restrict__ packB) {
  const int i = blockIdx.x * 256 + threadIdx.x;   // 0..131071
  const int lane = i & 63, nf = (i >> 6) & 3, kt = (i >> 8) & 63, wq = i >> 14;  // wq 0..7
  const int r15 = lane & 15, hi = lane >> 4;
  const int f = wq * 64 + nf * 16 + r15;
  const int k = kt * 32 + hi * 8;
  const float* src = w + (size_t)f * D_ + k;
  float4 v0 = *(const float4*)(src);
  float4 v1 = *(const float4*)(src + 4);
  u16 r[8] = { f2bf(v0.x), f2bf(v0.y), f2bf(v0.z), f2bf(v0.w),
               f2bf(v1.x), f2bf(v1.y), f2bf(v1.z), f2bf(v1.w) };
  *(uint4*)(packB + (size_t)i * 8) = *(const uint4*)r;
}

// ---- K4: GEMM [64 hw] x [512 f] x [K 2048], BK=64: 2 K-tiles per barrier ----
// 32 iters; per iter: [load B-pair(i+1), 8 ops] -> vmcnt(10) -> s_barrier ->
// [stage A-pair(i+2), 2 ops] -> setprio(1) 32 MFMA setprio(0).
// vmcnt(10) derivation: queue = A-pair(i)(2) B-pair(i)(8) | A-pair(i+1)(2)
// B-pair(i+1)(8); retire first 10, keep 10. 8 A-bufs x 4KB; WAR-safe since
// stage(i) overwrites pair(i-2) computed at iter i-2 (order: wait,barrier,
// stage,compute => barrier(i) implies compute(i-1) done on all waves).
__global__ __launch_bounds__(512) void k_gemm(const u16* __restrict__ packA,
    const u16* __restrict__ packB, const float* __restrict__ bias,
    float* __restrict__ outL) {
  const int n  = blockIdx.x >> 4;
  const int mtl = blockIdx.x & 15;
  const int mt = blockIdx.x;            // global 64-row tile index
  const int hw0 = mtl * 64;
  const int t = threadIdx.x;
  const int lane = t & 63, wv = t >> 6;
  const int r15 = lane & 15, hi = lane >> 4;

  __shared__ __align__(16) float smem_f[128 * 68];   // 34.8 KB; A bufs alias first 32 KB
  __shared__ float s_sq[8][64];
  __shared__ float s_rn[64];

  f32x4 acc[4][4];
  #pragma unroll
  for (int a = 0; a < 4; ++a)
    #pragma unroll
    for (int b = 0; b < 4; ++b) acc[a][b] = (f32x4){0.f, 0.f, 0.f, 0.f};

  const u16* asrc = packA + ((size_t)(mt * 64) * 4 + (wv & 3)) * 512 + lane * 8;
  const u16* bbase = packB + (size_t)wv * 131072 + lane * 8;

#define STAGE_A(KT) GLD_LDS16(asrc + (size_t)(KT) * 2048, \
    (char*)smem_f + ((KT) & 7) * 4096 + (wv & 3) * 1024)

  // prologue: B(0),B(1) then A(0..3)  [12 vm-ops]
  bf16x8 bc[4], bc2[4], bn[4], bn2[4];
  #pragma unroll
  for (int nf = 0; nf < 4; ++nf) bc[nf]  = *(const bf16x8*)(bbase + nf * 512);
  #pragma unroll
  for (int nf = 0; nf < 4; ++nf) bc2[nf] = *(const bf16x8*)(bbase + (4 + nf) * 512);
  __builtin_amdgcn_sched_barrier(0);
  #pragma unroll
  for (int q = 0; q < 4; ++q) STAGE_A(q);
  __builtin_amdgcn_sched_barrier(0);

  for (int i = 0; i < 32; ++i) {
    if (i + 1 < 32) {
      #pragma unroll
      for (int nf = 0; nf < 4; ++nf)
        bn[nf]  = *(const bf16x8*)(bbase + ((2 * i + 2) * 4 + nf) * 512);
      #pragma unroll
      for (int nf = 0; nf < 4; ++nf)
        bn2[nf] = *(const bf16x8*)(bbase + ((2 * i + 3) * 4 + nf) * 512);
    }
    __builtin_amdgcn_sched_barrier(0);
    if (i < 31) {
      asm volatile("s_waitcnt vmcnt(10)" ::: "memory");   // pair(i) retired
    } else {
      asm volatile("s_waitcnt vmcnt(0)" ::: "memory");
    }
    __builtin_amdgcn_sched_barrier(0);
    __builtin_amdgcn_s_barrier();                          // pair(i) visible
    __builtin_amdgcn_sched_barrier(0);
    if (i <= 29) { STAGE_A(2 * i + 4); STAGE_A(2 * i + 5); }
    __builtin_amdgcn_sched_barrier(0);

    const u16* sA0 = (const u16*)((const char*)smem_f + ((2 * i) & 7) * 4096);
    const u16* sA1 = (const u16*)((const char*)smem_f + ((2 * i + 1) & 7) * 4096);
    bf16x8 af0[4], af1[4];
    #pragma unroll
    for (int mf = 0; mf < 4; ++mf) {
      af0[mf] = *(const bf16x8*)(sA0 + mf * 512 + lane * 8);
      af1[mf] = *(const bf16x8*)(sA1 + mf * 512 + lane * 8);
    }
    __builtin_amdgcn_s_setprio(1);
    #pragma unroll
    for (int mf = 0; mf < 4; ++mf)
      #pragma unroll
      for (int nf = 0; nf < 4; ++nf)
        acc[mf][nf] = __builtin_amdgcn_mfma_f32_16x16x32_bf16(af0[mf], bc[nf], acc[mf][nf], 0, 0, 0);
    #pragma unroll
    for (int mf = 0; mf < 4; ++mf)
      #pragma unroll
      for (int nf = 0; nf < 4; ++nf)
        acc[mf][nf] = __builtin_amdgcn_mfma_f32_16x16x32_bf16(af1[mf], bc2[nf], acc[mf][nf], 0, 0, 0);
    __builtin_amdgcn_s_setprio(0);
    #pragma unroll
    for (int nf = 0; nf < 4; ++nf) { bc[nf] = bn[nf]; bc2[nf] = bn2[nf]; }
  }
#undef STAGE_A

  // epilogue: bias, per-row (hw) l2 norm over all 512 f, transposed store
  float badd[4];
  #pragma unroll
  for (int nf = 0; nf < 4; ++nf) badd[nf] = bias[wv * 64 + nf * 16 + r15];
  #pragma unroll
  for (int mf = 0; mf < 4; ++mf)
    #pragma unroll
    for (int nf = 0; nf < 4; ++nf)
      #pragma unroll
      for (int j = 0; j < 4; ++j) acc[mf][nf][j] += badd[nf];

  #pragma unroll
  for (int mf = 0; mf < 4; ++mf)
    #pragma unroll
    for (int j = 0; j < 4; ++j) {
      float s = 0.f;
      #pragma unroll
      for (int nf = 0; nf < 4; ++nf) { float v = acc[mf][nf][j]; s += v * v; }
      s += __shfl_xor(s, 1); s += __shfl_xor(s, 2); s += __shfl_xor(s, 4); s += __shfl_xor(s, 8);
      if ((lane & 15) == 0) s_sq[wv][mf * 16 + hi * 4 + j] = s;
    }
  __syncthreads();
  if (t < 64) {
    float s = 0.f;
    #pragma unroll
    for (int w8 = 0; w8 < 8; ++w8) s += s_sq[w8][t];
    s_rn[t] = 1.0f / fmaxf(sqrtf(s), 1e-12f);
  }
  __syncthreads();

  float* ct = smem_f;   // [128 f-rows][68] fp32
  for (int nf = 0; nf < 4; ++nf) {
    const int fi = wv * 16 + r15;
    #pragma unroll
    for (int mf = 0; mf < 4; ++mf)
      #pragma unroll
      for (int j = 0; j < 4; ++j) {
        int m = mf * 16 + hi * 4 + j;
        ct[fi * 68 + m] = acc[mf][nf][j] * s_rn[m];
      }
    __syncthreads();
    {
      int fr = t >> 2, mq = t & 3;
      int f = (fr >> 4) * 64 + nf * 16 + (fr & 15);
      float* dst = outL + ((size_t)(n * F_ + f)) * HW_ + hw0 + mq * 16;
      const float* srcp = ct + fr * 68 + mq * 16;
      float4 a0 = *(const float4*)(srcp);
      float4 a1 = *(const float4*)(srcp + 4);
      float4 a2 = *(const float4*)(srcp + 8);
      float4 a3 = *(const float4*)(srcp + 12);
      *(float4*)(dst) = a0; *(float4*)(dst + 4) = a1;
      *(float4*)(dst + 8) = a2; *(float4*)(dst + 12) = a3;
    }
    __syncthreads();
  }
}

// ---- K5: GeM finalize: gg = (gbuf/1024)^(1/p) ----
__global__ __launch_bounds__(256) void k_gem_fin(const float* __restrict__ gbuf,
    const float* __restrict__ pvec, float* __restrict__ gg) {
  int i = blockIdx.x * 256 + threadIdx.x;
  float p = pvec[0];
  float m = gbuf[i] * (1.0f / 1024.0f);
  gg[i] = (p == 3.0f) ? cbrtf(m) : powf(m, 1.0f / p);
}

// ---- K6: gproj[n][f] = dot(gg[n], W[f]) + b[f] ----
__global__ __launch_bounds__(256) void k_gproj(const float* __restrict__ w,
    const float* __restrict__ bias, const float* __restrict__ gg,
    float* __restrict__ gproj) {
  const int f = blockIdx.x;
  const int t = threadIdx.x;
  float wreg[8];
  #pragma unroll
  for (int j = 0; j < 8; ++j) wreg[j] = w[(size_t)f * D_ + t + j * 256];
  __shared__ float red[4];
  const int lane = t & 63, wv = t >> 6;
  for (int n = 0; n < N_; ++n) {
    float s = 0.f;
    #pragma unroll
    for (int j = 0; j < 8; ++j) s += wreg[j] * gg[n * D_ + t + j * 256];
    #pragma unroll
    for (int off = 32; off >= 1; off >>= 1) s += __shfl_down(s, off);
    if (lane == 0) red[wv] = s;
    __syncthreads();
    if (t == 0) gproj[n * F_ + f] = red[0] + red[1] + red[2] + red[3] + bias[f];
    __syncthreads();
  }
}

// ---- K7: l2norm g rows -> d_out[0:8192] ----
__global__ __launch_bounds__(512) void k_gnorm(const float* __restrict__ gproj, float* __restrict__ outg) {
  const int n = blockIdx.x;
  const int t = threadIdx.x;
  float v = gproj[n * F_ + t];
  float s = v * v;
  const int lane = t & 63, wv = t >> 6;
  #pragma unroll
  for (int off = 32; off >= 1; off >>= 1) s += __shfl_down(s, off);
  __shared__ float red[8];
  __shared__ float rtot;
  if (lane == 0) red[wv] = s;
  __syncthreads();
  if (t == 0) {
    float a = 0.f;
    #pragma unroll
    for (int i = 0; i < 8; ++i) a += red[i];
    rtot = 1.0f / fmaxf(sqrtf(a), 1e-12f);
  }
  __syncthreads();
  outg[n * F_ + t] = v * rtot;
}

extern "C" void kernel_launch(void* const* d_in, const int* in_sizes, int n_in,
                              void* d_out, int out_size, void* d_ws, size_t ws_size,
                              hipStream_t stream) {
  const float* x  = (const float*)d_in[0];
  const float* pw = (const float*)d_in[1];
  const float* pb = (const float*)d_in[2];
  const float* pv = (const float*)d_in[3];
  float* out = (float*)d_out;

  char* ws = (char*)d_ws;
  float* sumsq = (float*)ws;                                   // 64 KB
  float* gbuf  = (float*)(ws + 65536);                         // 128 KB
  float* gg    = (float*)(ws + 65536 + 131072);                // 128 KB
  float* gproj = (float*)(ws + 65536 + 2 * 131072);            // 32 KB
  u16*   packB = (u16*)(ws + 65536 + 2 * 131072 + 32768);      // 2 MiB
  u16*   packA = (u16*)(ws + 4u * 1024u * 1024u);              // 64 MiB

  k_zero<<<dim3(48), dim3(256), 0, stream>>>(sumsq);           // sumsq + gbuf
  k_sumsq<<<dim3(16, 32), dim3(256), 0, stream>>>(x, sumsq);
  k_wconv<<<dim3(512), dim3(256), 0, stream>>>(pw, packB);
  k_box2<<<dim3(16, 8, 32), dim3(256), 0, stream>>>(x, sumsq, pv, gbuf, packA);
  k_gem_fin<<<dim3(128), dim3(256), 0, stream>>>(gbuf, pv, gg);
  k_gproj<<<dim3(512), dim3(256), 0, stream>>>(pw, pb, gg, gproj);
  k_gnorm<<<dim3(16), dim3(512), 0, stream>>>(gproj, out);
  k_gemm<<<dim3(256), dim3(512), 0, stream>>>(packA, packB, pb, out + N_ * F_);
}

// Round 15
// 141.352 us; speedup vs baseline: 1.0202x; 1.0202x over previous
//
#include <hip/hip_runtime.h>
#include <hip/hip_bf16.h>

#define N_ 16
#define D_ 2048
#define H_ 32
#define W_ 32
#define HW_ 1024
#define F_ 512

typedef unsigned short u16;
typedef unsigned int u32;
typedef __attribute__((ext_vector_type(8))) short bf16x8;
typedef __attribute__((ext_vector_type(4))) float f32x4;

__device__ __forceinline__ u16 f2bf(float f) {
  union { float fv; u32 u; } c; c.fv = f;
  u32 u = c.u;
  u32 r = (u + 0x7fffu + ((u >> 16) & 1u)) >> 16;   // RNE
  return (u16)r;
}
__device__ __forceinline__ u32 f2bf2(float lo, float hi) {
  return (u32)f2bf(lo) | ((u32)f2bf(hi) << 16);
}

#define GLD_LDS16(gp, lp) __builtin_amdgcn_global_load_lds( \
    (const __attribute__((address_space(1))) void*)(gp), \
    (__attribute__((address_space(3))) void*)(lp), 16, 0, 0)

// ---- K0: zero sumsq+gbuf (192 KB contiguous) ----
__global__ __launch_bounds__(256) void k_zero(float* __restrict__ p) {
  int i = blockIdx.x * 256 + threadIdx.x;
  ((float4*)p)[i] = (float4){0.f, 0.f, 0.f, 0.f};
}

// ---- K1: sum of squares over channel dim -> sumsq[n][hw] (atomic partials) ----
__global__ __launch_bounds__(256) void k_sumsq(const float* __restrict__ x, float* __restrict__ sumsq) {
  const int n = blockIdx.x;        // 16
  const int dc = blockIdx.y;       // 32 chunks x 64 d
  const int t = threadIdx.x;
  const float* xp = x + ((size_t)n * D_ + (size_t)dc * 64) * HW_;
  float s0 = 0.f, s1 = 0.f, s2 = 0.f, s3 = 0.f;
  for (int d = 0; d < 64; ++d) {
    const float* row = xp + (size_t)d * HW_;
    float v0 = row[t], v1 = row[t + 256], v2 = row[t + 512], v3 = row[t + 768];
    s0 += v0 * v0; s1 += v1 * v1; s2 += v2 * v2; s3 += v3 * v3;
  }
  atomicAdd(&sumsq[n * HW_ + t      ], s0);
  atomicAdd(&sumsq[n * HW_ + t + 256], s1);
  atomicAdd(&sumsq[n * HW_ + t + 512], s2);
  atomicAdd(&sumsq[n * HW_ + t + 768], s3);
}

// ---- K2: fused-dj float4 box + GeM partials ----
// grid (n=16, ht=8, dc=32), block 256: w4 = t&7 (w-quad), dg = t>>3 (d-pair).
// All 24 float4 x-loads issued up front (2x MLP vs r13); d-pair packed to u32
// at conversion -> 16 ds_write_b32 (was 32 ds_write_b16). sbox u32 [128][34]:
// per-write-instr banks = (8*w4+dg)%32 -> exact 2-way (free, m136).
__global__ __launch_bounds__(256) void k_box2(const float* __restrict__ x,
    const float* __restrict__ sumsq, const float* __restrict__ pvec,
    float* __restrict__ gbuf, u16* __restrict__ packA) {
  const int n = blockIdx.x, ht = blockIdx.y, dc = blockIdx.z;
  const int h0 = ht * 4, d0 = dc * 64;
  const int t = threadIdx.x;
  const int w4 = t & 7, dg = t >> 3;
  const int wq = w4 * 4;
  const float p = pvec[0];
  const bool p3 = (p == 3.0f);

  __shared__ __align__(16) u32 sbox[128 * 34];   // [hw 128][d-pair 32 pad->34] = 17408 B
  __shared__ __align__(16) float rnl[6][32];

  if (t < 192) {
    int jj = t >> 5, w = t & 31;
    int hp = h0 - 1 + jj;
    float r = 0.f;
    if (hp >= 0 && hp < H_) r = 1.0f / fmaxf(sqrtf(sumsq[n * HW_ + hp * W_ + w]), 1e-12f);
    rnl[jj][w] = r;
  }
  __syncthreads();

  const float* base0 = x + ((size_t)(n * D_ + d0 + dg * 2)) * HW_ + wq;
  const float* base1 = base0 + HW_;

  float4 v0[6], v1[6];
  #pragma unroll
  for (int jj = 0; jj < 6; ++jj) {
    int hp = h0 - 1 + jj;
    if (hp >= 0 && hp < H_) {
      float4 a = *(const float4*)(base0 + hp * W_);
      float4 b = *(const float4*)(base1 + hp * W_);
      float4 rr = *(const float4*)(&rnl[jj][wq]);
      v0[jj].x = a.x * rr.x; v0[jj].y = a.y * rr.y; v0[jj].z = a.z * rr.z; v0[jj].w = a.w * rr.w;
      v1[jj].x = b.x * rr.x; v1[jj].y = b.y * rr.y; v1[jj].z = b.z * rr.z; v1[jj].w = b.w * rr.w;
    } else {
      v0[jj] = (float4){0.f, 0.f, 0.f, 0.f};
      v1[jj] = (float4){0.f, 0.f, 0.f, 0.f};
    }
  }

  // GeM partials over the 4 owned rows (jj=1..4)
  float g0 = 0.f, g1 = 0.f;
  #pragma unroll
  for (int jj = 1; jj <= 4; ++jj) {
    float c0x = fmaxf(v0[jj].x, 1e-6f), c0y = fmaxf(v0[jj].y, 1e-6f);
    float c0z = fmaxf(v0[jj].z, 1e-6f), c0w = fmaxf(v0[jj].w, 1e-6f);
    float c1x = fmaxf(v1[jj].x, 1e-6f), c1y = fmaxf(v1[jj].y, 1e-6f);
    float c1z = fmaxf(v1[jj].z, 1e-6f), c1w = fmaxf(v1[jj].w, 1e-6f);
    if (p3) {
      g0 += c0x * c0x * c0x + c0y * c0y * c0y + c0z * c0z * c0z + c0w * c0w * c0w;
      g1 += c1x * c1x * c1x + c1y * c1y * c1y + c1z * c1z * c1z + c1w * c1w * c1w;
    } else {
      g0 += __powf(c0x, p) + __powf(c0y, p) + __powf(c0z, p) + __powf(c0w, p);
      g1 += __powf(c1x, p) + __powf(c1y, p) + __powf(c1z, p) + __powf(c1w, p);
    }
  }

  // horizontal 3-tap within 8-lane w4 groups (both d's)
  #pragma unroll
  for (int jj = 0; jj < 6; ++jj) {
    float lf0 = __shfl_up(v0[jj].w, 1, 8), rf0 = __shfl_down(v0[jj].x, 1, 8);
    float lf1 = __shfl_up(v1[jj].w, 1, 8), rf1 = __shfl_down(v1[jj].x, 1, 8);
    if (w4 == 0) { lf0 = 0.f; lf1 = 0.f; }
    if (w4 == 7) { rf0 = 0.f; rf1 = 0.f; }
    float4 h0v, h1v;
    h0v.x = lf0 + v0[jj].x + v0[jj].y;
    h0v.y = v0[jj].x + v0[jj].y + v0[jj].z;
    h0v.z = v0[jj].y + v0[jj].z + v0[jj].w;
    h0v.w = v0[jj].z + v0[jj].w + rf0;
    h1v.x = lf1 + v1[jj].x + v1[jj].y;
    h1v.y = v1[jj].x + v1[jj].y + v1[jj].z;
    h1v.z = v1[jj].y + v1[jj].z + v1[jj].w;
    h1v.w = v1[jj].z + v1[jj].w + rf1;
    v0[jj] = h0v; v1[jj] = h1v;
  }

  // vertical 3-tap + packed u32 LDS stage
  #pragma unroll
  for (int k = 0; k < 4; ++k) {
    float4 b0, b1;
    b0.x = v0[k].x + v0[k + 1].x + v0[k + 2].x;
    b0.y = v0[k].y + v0[k + 1].y + v0[k + 2].y;
    b0.z = v0[k].z + v0[k + 1].z + v0[k + 2].z;
    b0.w = v0[k].w + v0[k + 1].w + v0[k + 2].w;
    b1.x = v1[k].x + v1[k + 1].x + v1[k + 2].x;
    b1.y = v1[k].y + v1[k + 1].y + v1[k + 2].y;
    b1.z = v1[k].z + v1[k + 1].z + v1[k + 2].z;
    b1.w = v1[k].w + v1[k + 1].w + v1[k + 2].w;
    const int rb = k * 32 + wq;
    sbox[(rb + 0) * 34 + dg] = f2bf2(b0.x, b1.x);
    sbox[(rb + 1) * 34 + dg] = f2bf2(b0.y, b1.y);
    sbox[(rb + 2) * 34 + dg] = f2bf2(b0.z, b1.z);
    sbox[(rb + 3) * 34 + dg] = f2bf2(b0.w, b1.w);
  }
  __syncthreads();

  // packed writeout (r8/r13 layout, byte-identical): thread -> 32 bf16 of one hw row
  {
    const int r = t >> 1, half = t & 1;
    const u32* srcp = sbox + r * 34 + half * 16;
    uint2 a[8];
    #pragma unroll
    for (int q = 0; q < 8; ++q) a[q] = *(const uint2*)(srcp + q * 2);
    const int mt = n * 16 + ht * 2 + (r >> 6);
    const int mf = (r >> 4) & 3, r15 = r & 15;
    const int kt = dc * 2 + half;
    u16* dst = packA + ((size_t)(mt * 64 + kt) * 4 + mf) * 512 + r15 * 8;
    #pragma unroll
    for (int q = 0; q < 4; ++q) {        // q = hi
      uint4 b;
      b.x = a[2 * q].x; b.y = a[2 * q].y; b.z = a[2 * q + 1].x; b.w = a[2 * q + 1].y;
      *(uint4*)(dst + q * 128) = b;
    }
  }

  // GeM reduce over the 8 w4-lanes
  {
    float u0 = g0, u1 = g1;
    u0 += __shfl_xor(u0, 1, 8); u1 += __shfl_xor(u1, 1, 8);
    u0 += __shfl_xor(u0, 2, 8); u1 += __shfl_xor(u1, 2, 8);
    u0 += __shfl_xor(u0, 4, 8); u1 += __shfl_xor(u1, 4, 8);
    if (w4 == 0) {
      atomicAdd(&gbuf[n * D_ + d0 + dg * 2    ], u0);
      atomicAdd(&gbuf[n * D_ + d0 + dg * 2 + 1], u1);
    }
  }
}

// ---- K3: proj_w fp32 -> bf16, fragment-packed: packB[wq][kt][nf][lane][8] ----
__global__ __launch_bounds__(256) void k_wconv(const float* __restrict__ w, u16* __restrict__ packB) {
  const int i = blockIdx.x * 256 + threadIdx.x;   // 0..131071
  const int lane = i & 63, nf = (i >> 6) & 3, kt = (i >> 8) & 63, wq = i >> 14;  // wq 0..7
  const int r15 = lane & 15, hi = lane >> 4;
  const int f = wq * 64 + nf * 16 + r15;
  const int k = kt * 32 + hi * 8;
  const float* src = w + (size_t)f * D_ + k;
  float4 v0 = *(const float4*)(src);
  float4 v1 = *(const float4*)(src + 4);
  u16 r[8] = { f2bf(v0.x), f2bf(v0.y), f2bf(v0.z), f2bf(v0.w),
               f2bf(v1.x), f2bf(v1.y), f2bf(v1.z), f2bf(v1.w) };
  *(uint4*)(packB + (size_t)i * 8) = *(const uint4*)r;
}

// ---- K4: GEMM [64 hw] x [512 f] x [K 2048] (r13/r8 form, best measured) ----
// 4-buf A via global_load_lds, B->reg lead-1, counted vmcnt 5/4/0, one
// s_barrier per step; all loads contiguous 1KB dwordx4; ds_reads lane-linear.
__global__ __launch_bounds__(512) void k_gemm(const u16* __restrict__ packA,
    const u16* __restrict__ packB, const float* __restrict__ bias,
    float* __restrict__ outL) {
  const int n  = blockIdx.x >> 4;
  const int mtl = blockIdx.x & 15;
  const int mt = blockIdx.x;            // global 64-row tile index
  const int hw0 = mtl * 64;
  const int t = threadIdx.x;
  const int lane = t & 63, wv = t >> 6;
  const int r15 = lane & 15, hi = lane >> 4;

  __shared__ __align__(16) float smem_f[128 * 68];   // 34.8 KB; A bufs alias first 16 KB
  __shared__ float s_sq[8][64];
  __shared__ float s_rn[64];

  f32x4 acc[4][4];
  #pragma unroll
  for (int a = 0; a < 4; ++a)
    #pragma unroll
    for (int b = 0; b < 4; ++b) acc[a][b] = (f32x4){0.f, 0.f, 0.f, 0.f};

  const u16* asrc = packA + ((size_t)(mt * 64) * 4 + (wv & 3)) * 512 + lane * 8;
  const u16* bbase = packB + (size_t)wv * 131072 + lane * 8;

#define STAGE_A(KT) GLD_LDS16(asrc + (size_t)(KT) * 2048, \
    (char*)smem_f + ((KT) & 3) * 4096 + (wv & 3) * 1024)

  STAGE_A(0);
  STAGE_A(1);
  bf16x8 bc[4], bn[4];
  #pragma unroll
  for (int nf = 0; nf < 4; ++nf) bc[nf] = *(const bf16x8*)(bbase + nf * 512);

  for (int kt = 0; kt < 64; ++kt) {
    if (kt + 2 < 64) STAGE_A(kt + 2);
    if (kt + 1 < 64) {
      #pragma unroll
      for (int nf = 0; nf < 4; ++nf)
        bn[nf] = *(const bf16x8*)(bbase + ((kt + 1) * 4 + nf) * 512);
    }
    __builtin_amdgcn_sched_barrier(0);
    if (kt < 62) {
      asm volatile("s_waitcnt vmcnt(5)" ::: "memory");   // A(kt)+B(kt) retired
    } else if (kt == 62) {
      asm volatile("s_waitcnt vmcnt(4)" ::: "memory");
    } else {
      asm volatile("s_waitcnt vmcnt(0)" ::: "memory");
    }
    __builtin_amdgcn_sched_barrier(0);
    __builtin_amdgcn_s_barrier();                         // A tile kt visible
    __builtin_amdgcn_sched_barrier(0);

    const u16* sA = (const u16*)((const char*)smem_f + (kt & 3) * 4096);
    bf16x8 af[4];
    #pragma unroll
    for (int mf = 0; mf < 4; ++mf)
      af[mf] = *(const bf16x8*)(sA + mf * 512 + lane * 8);
    #pragma unroll
    for (int mf = 0; mf < 4; ++mf)
      #pragma unroll
      for (int nf = 0; nf < 4; ++nf)
        acc[mf][nf] = __builtin_amdgcn_mfma_f32_16x16x32_bf16(af[mf], bc[nf], acc[mf][nf], 0, 0, 0);
    #pragma unroll
    for (int nf = 0; nf < 4; ++nf) bc[nf] = bn[nf];
  }
#undef STAGE_A

  // epilogue: bias, per-row (hw) l2 norm over all 512 f, transposed store
  float badd[4];
  #pragma unroll
  for (int nf = 0; nf < 4; ++nf) badd[nf] = bias[wv * 64 + nf * 16 + r15];
  #pragma unroll
  for (int mf = 0; mf < 4; ++mf)
    #pragma unroll
    for (int nf = 0; nf < 4; ++nf)
      #pragma unroll
      for (int j = 0; j < 4; ++j) acc[mf][nf][j] += badd[nf];

  #pragma unroll
  for (int mf = 0; mf < 4; ++mf)
    #pragma unroll
    for (int j = 0; j < 4; ++j) {
      float s = 0.f;
      #pragma unroll
      for (int nf = 0; nf < 4; ++nf) { float v = acc[mf][nf][j]; s += v * v; }
      s += __shfl_xor(s, 1); s += __shfl_xor(s, 2); s += __shfl_xor(s, 4); s += __shfl_xor(s, 8);
      if ((lane & 15) == 0) s_sq[wv][mf * 16 + hi * 4 + j] = s;
    }
  __syncthreads();
  if (t < 64) {
    float s = 0.f;
    #pragma unroll
    for (int w8 = 0; w8 < 8; ++w8) s += s_sq[w8][t];
    s_rn[t] = 1.0f / fmaxf(sqrtf(s), 1e-12f);
  }
  __syncthreads();

  float* ct = smem_f;   // [128 f-rows][68] fp32
  for (int nf = 0; nf < 4; ++nf) {
    const int fi = wv * 16 + r15;
    #pragma unroll
    for (int mf = 0; mf < 4; ++mf)
      #pragma unroll
      for (int j = 0; j < 4; ++j) {
        int m = mf * 16 + hi * 4 + j;
        ct[fi * 68 + m] = acc[mf][nf][j] * s_rn[m];
      }
    __syncthreads();
    {
      int fr = t >> 2, mq = t & 3;
      int f = (fr >> 4) * 64 + nf * 16 + (fr & 15);
      float* dst = outL + ((size_t)(n * F_ + f)) * HW_ + hw0 + mq * 16;
      const float* srcp = ct + fr * 68 + mq * 16;
      float4 a0 = *(const float4*)(srcp);
      float4 a1 = *(const float4*)(srcp + 4);
      float4 a2 = *(const float4*)(srcp + 8);
      float4 a3 = *(const float4*)(srcp + 12);
      *(float4*)(dst) = a0; *(float4*)(dst + 4) = a1;
      *(float4*)(dst + 8) = a2; *(float4*)(dst + 12) = a3;
    }
    __syncthreads();
  }
}

// ---- K5: GeM finalize: gg = (gbuf/1024)^(1/p) ----
__global__ __launch_bounds__(256) void k_gem_fin(const float* __restrict__ gbuf,
    const float* __restrict__ pvec, float* __restrict__ gg) {
  int i = blockIdx.x * 256 + threadIdx.x;
  float p = pvec[0];
  float m = gbuf[i] * (1.0f / 1024.0f);
  gg[i] = (p == 3.0f) ? cbrtf(m) : powf(m, 1.0f / p);
}

// ---- K6: gproj[n][f] = dot(gg[n], W[f]) + b[f] ----
__global__ __launch_bounds__(256) void k_gproj(const float* __restrict__ w,
    const float* __restrict__ bias, const float* __restrict__ gg,
    float* __restrict__ gproj) {
  const int f = blockIdx.x;
  const int t = threadIdx.x;
  float wreg[8];
  #pragma unroll
  for (int j = 0; j < 8; ++j) wreg[j] = w[(size_t)f * D_ + t + j * 256];
  __shared__ float red[4];
  const int lane = t & 63, wv = t >> 6;
  for (int n = 0; n < N_; ++n) {
    float s = 0.f;
    #pragma unroll
    for (int j = 0; j < 8; ++j) s += wreg[j] * gg[n * D_ + t + j * 256];
    #pragma unroll
    for (int off = 32; off >= 1; off >>= 1) s += __shfl_down(s, off);
    if (lane == 0) red[wv] = s;
    __syncthreads();
    if (t == 0) gproj[n * F_ + f] = red[0] + red[1] + red[2] + red[3] + bias[f];
    __syncthreads();
  }
}

// ---- K7: l2norm g rows -> d_out[0:8192] ----
__global__ __launch_bounds__(512) void k_gnorm(const float* __restrict__ gproj, float* __restrict__ outg) {
  const int n = blockIdx.x;
  const int t = threadIdx.x;
  float v = gproj[n * F_ + t];
  float s = v * v;
  const int lane = t & 63, wv = t >> 6;
  #pragma unroll
  for (int off = 32; off >= 1; off >>= 1) s += __shfl_down(s, off);
  __shared__ float red[8];
  __shared__ float rtot;
  if (lane == 0) red[wv] = s;
  __syncthreads();
  if (t == 0) {
    float a = 0.f;
    #pragma unroll
    for (int i = 0; i < 8; ++i) a += red[i];
    rtot = 1.0f / fmaxf(sqrtf(a), 1e-12f);
  }
  __syncthreads();
  outg[n * F_ + t] = v * rtot;
}

extern "C" void kernel_launch(void* const* d_in, const int* in_sizes, int n_in,
                              void* d_out, int out_size, void* d_ws, size_t ws_size,
                              hipStream_t stream) {
  const float* x  = (const float*)d_in[0];
  const float* pw = (const float*)d_in[1];
  const float* pb = (const float*)d_in[2];
  const float* pv = (const float*)d_in[3];
  float* out = (float*)d_out;

  char* ws = (char*)d_ws;
  float* sumsq = (float*)ws;                                   // 64 KB
  float* gbuf  = (float*)(ws + 65536);                         // 128 KB
  float* gg    = (float*)(ws + 65536 + 131072);                // 128 KB
  float* gproj = (float*)(ws + 65536 + 2 * 131072);            // 32 KB
  u16*   packB = (u16*)(ws + 65536 + 2 * 131072 + 32768);      // 2 MiB
  u16*   packA = (u16*)(ws + 4u * 1024u * 1024u);              // 64 MiB

  k_zero<<<dim3(48), dim3(256), 0, stream>>>(sumsq);           // sumsq + gbuf
  k_sumsq<<<dim3(16, 32), dim3(256), 0, stream>>>(x, sumsq);
  k_wconv<<<dim3(512), dim3(256), 0, stream>>>(pw, packB);
  k_box2<<<dim3(16, 8, 32), dim3(256), 0, stream>>>(x, sumsq, pv, gbuf, packA);
  k_gem_fin<<<dim3(128), dim3(256), 0, stream>>>(gbuf, pv, gg);
  k_gproj<<<dim3(512), dim3(256), 0, stream>>>(pw, pb, gg, gproj);
  k_gnorm<<<dim3(16), dim3(512), 0, stream>>>(gproj, out);
  k_gemm<<<dim3(256), dim3(512), 0, stream>>>(packA, packB, pb, out + N_ * F_);
}

// Round 16
// 141.079 us; speedup vs baseline: 1.0222x; 1.0019x over previous
//
#include <hip/hip_runtime.h>
#include <hip/hip_bf16.h>

#define N_ 16
#define D_ 2048
#define H_ 32
#define W_ 32
#define HW_ 1024
#define F_ 512

typedef unsigned short u16;
typedef unsigned int u32;
typedef __attribute__((ext_vector_type(8))) short bf16x8;
typedef __attribute__((ext_vector_type(4))) float f32x4;

// HW RNE conversion (compiler emits native cvt; fuses pairs to v_cvt_pk_bf16_f32).
// m240: scalar cast is the fast path; do NOT hand-write inline-asm cvt_pk.
__device__ __forceinline__ u16 f2bf(float f) {
  __hip_bfloat16 h = __float2bfloat16(f);
  union { __hip_bfloat16 h; u16 u; } c; c.h = h;
  return c.u;
}
__device__ __forceinline__ u32 f2bf2(float lo, float hi) {
  return (u32)f2bf(lo) | ((u32)f2bf(hi) << 16);
}

#define GLD_LDS16(gp, lp) __builtin_amdgcn_global_load_lds( \
    (const __attribute__((address_space(1))) void*)(gp), \
    (__attribute__((address_space(3))) void*)(lp), 16, 0, 0)

// ---- K0: zero sumsq+gbuf (192 KB contiguous) ----
__global__ __launch_bounds__(256) void k_zero(float* __restrict__ p) {
  int i = blockIdx.x * 256 + threadIdx.x;
  ((float4*)p)[i] = (float4){0.f, 0.f, 0.f, 0.f};
}

// ---- K1: sum of squares over channel dim -> sumsq[n][hw] (atomic partials) ----
__global__ __launch_bounds__(256) void k_sumsq(const float* __restrict__ x, float* __restrict__ sumsq) {
  const int n = blockIdx.x;        // 16
  const int dc = blockIdx.y;       // 32 chunks x 64 d
  const int t = threadIdx.x;
  const float* xp = x + ((size_t)n * D_ + (size_t)dc * 64) * HW_;
  float s0 = 0.f, s1 = 0.f, s2 = 0.f, s3 = 0.f;
  for (int d = 0; d < 64; ++d) {
    const float* row = xp + (size_t)d * HW_;
    float v0 = row[t], v1 = row[t + 256], v2 = row[t + 512], v3 = row[t + 768];
    s0 += v0 * v0; s1 += v1 * v1; s2 += v2 * v2; s3 += v3 * v3;
  }
  atomicAdd(&sumsq[n * HW_ + t      ], s0);
  atomicAdd(&sumsq[n * HW_ + t + 256], s1);
  atomicAdd(&sumsq[n * HW_ + t + 512], s2);
  atomicAdd(&sumsq[n * HW_ + t + 768], s3);
}

// ---- K2: fused-dj float4 box + GeM partials (r15 form, HW cvt) ----
__global__ __launch_bounds__(256) void k_box2(const float* __restrict__ x,
    const float* __restrict__ sumsq, const float* __restrict__ pvec,
    float* __restrict__ gbuf, u16* __restrict__ packA) {
  const int n = blockIdx.x, ht = blockIdx.y, dc = blockIdx.z;
  const int h0 = ht * 4, d0 = dc * 64;
  const int t = threadIdx.x;
  const int w4 = t & 7, dg = t >> 3;
  const int wq = w4 * 4;
  const float p = pvec[0];
  const bool p3 = (p == 3.0f);

  __shared__ __align__(16) u32 sbox[128 * 34];   // [hw 128][d-pair 32 pad->34]
  __shared__ __align__(16) float rnl[6][32];

  if (t < 192) {
    int jj = t >> 5, w = t & 31;
    int hp = h0 - 1 + jj;
    float r = 0.f;
    if (hp >= 0 && hp < H_) r = 1.0f / fmaxf(sqrtf(sumsq[n * HW_ + hp * W_ + w]), 1e-12f);
    rnl[jj][w] = r;
  }
  __syncthreads();

  const float* base0 = x + ((size_t)(n * D_ + d0 + dg * 2)) * HW_ + wq;
  const float* base1 = base0 + HW_;

  float4 v0[6], v1[6];
  #pragma unroll
  for (int jj = 0; jj < 6; ++jj) {
    int hp = h0 - 1 + jj;
    if (hp >= 0 && hp < H_) {
      float4 a = *(const float4*)(base0 + hp * W_);
      float4 b = *(const float4*)(base1 + hp * W_);
      float4 rr = *(const float4*)(&rnl[jj][wq]);
      v0[jj].x = a.x * rr.x; v0[jj].y = a.y * rr.y; v0[jj].z = a.z * rr.z; v0[jj].w = a.w * rr.w;
      v1[jj].x = b.x * rr.x; v1[jj].y = b.y * rr.y; v1[jj].z = b.z * rr.z; v1[jj].w = b.w * rr.w;
    } else {
      v0[jj] = (float4){0.f, 0.f, 0.f, 0.f};
      v1[jj] = (float4){0.f, 0.f, 0.f, 0.f};
    }
  }

  // GeM partials over the 4 owned rows (jj=1..4)
  float g0 = 0.f, g1 = 0.f;
  #pragma unroll
  for (int jj = 1; jj <= 4; ++jj) {
    float c0x = fmaxf(v0[jj].x, 1e-6f), c0y = fmaxf(v0[jj].y, 1e-6f);
    float c0z = fmaxf(v0[jj].z, 1e-6f), c0w = fmaxf(v0[jj].w, 1e-6f);
    float c1x = fmaxf(v1[jj].x, 1e-6f), c1y = fmaxf(v1[jj].y, 1e-6f);
    float c1z = fmaxf(v1[jj].z, 1e-6f), c1w = fmaxf(v1[jj].w, 1e-6f);
    if (p3) {
      g0 += c0x * c0x * c0x + c0y * c0y * c0y + c0z * c0z * c0z + c0w * c0w * c0w;
      g1 += c1x * c1x * c1x + c1y * c1y * c1y + c1z * c1z * c1z + c1w * c1w * c1w;
    } else {
      g0 += __powf(c0x, p) + __powf(c0y, p) + __powf(c0z, p) + __powf(c0w, p);
      g1 += __powf(c1x, p) + __powf(c1y, p) + __powf(c1z, p) + __powf(c1w, p);
    }
  }

  // horizontal 3-tap within 8-lane w4 groups (both d's)
  #pragma unroll
  for (int jj = 0; jj < 6; ++jj) {
    float lf0 = __shfl_up(v0[jj].w, 1, 8), rf0 = __shfl_down(v0[jj].x, 1, 8);
    float lf1 = __shfl_up(v1[jj].w, 1, 8), rf1 = __shfl_down(v1[jj].x, 1, 8);
    if (w4 == 0) { lf0 = 0.f; lf1 = 0.f; }
    if (w4 == 7) { rf0 = 0.f; rf1 = 0.f; }
    float4 h0v, h1v;
    h0v.x = lf0 + v0[jj].x + v0[jj].y;
    h0v.y = v0[jj].x + v0[jj].y + v0[jj].z;
    h0v.z = v0[jj].y + v0[jj].z + v0[jj].w;
    h0v.w = v0[jj].z + v0[jj].w + rf0;
    h1v.x = lf1 + v1[jj].x + v1[jj].y;
    h1v.y = v1[jj].x + v1[jj].y + v1[jj].z;
    h1v.z = v1[jj].y + v1[jj].z + v1[jj].w;
    h1v.w = v1[jj].z + v1[jj].w + rf1;
    v0[jj] = h0v; v1[jj] = h1v;
  }

  // vertical 3-tap + packed u32 LDS stage
  #pragma unroll
  for (int k = 0; k < 4; ++k) {
    float4 b0, b1;
    b0.x = v0[k].x + v0[k + 1].x + v0[k + 2].x;
    b0.y = v0[k].y + v0[k + 1].y + v0[k + 2].y;
    b0.z = v0[k].z + v0[k + 1].z + v0[k + 2].z;
    b0.w = v0[k].w + v0[k + 1].w + v0[k + 2].w;
    b1.x = v1[k].x + v1[k + 1].x + v1[k + 2].x;
    b1.y = v1[k].y + v1[k + 1].y + v1[k + 2].y;
    b1.z = v1[k].z + v1[k + 1].z + v1[k + 2].z;
    b1.w = v1[k].w + v1[k + 1].w + v1[k + 2].w;
    const int rb = k * 32 + wq;
    sbox[(rb + 0) * 34 + dg] = f2bf2(b0.x, b1.x);
    sbox[(rb + 1) * 34 + dg] = f2bf2(b0.y, b1.y);
    sbox[(rb + 2) * 34 + dg] = f2bf2(b0.z, b1.z);
    sbox[(rb + 3) * 34 + dg] = f2bf2(b0.w, b1.w);
  }
  __syncthreads();

  // packed writeout (r8/r13 layout): thread -> 32 bf16 of one hw row
  {
    const int r = t >> 1, half = t & 1;
    const u32* srcp = sbox + r * 34 + half * 16;
    uint2 a[8];
    #pragma unroll
    for (int q = 0; q < 8; ++q) a[q] = *(const uint2*)(srcp + q * 2);
    const int mt = n * 16 + ht * 2 + (r >> 6);
    const int mf = (r >> 4) & 3, r15 = r & 15;
    const int kt = dc * 2 + half;
    u16* dst = packA + ((size_t)(mt * 64 + kt) * 4 + mf) * 512 + r15 * 8;
    #pragma unroll
    for (int q = 0; q < 4; ++q) {        // q = hi
      uint4 b;
      b.x = a[2 * q].x; b.y = a[2 * q].y; b.z = a[2 * q + 1].x; b.w = a[2 * q + 1].y;
      *(uint4*)(dst + q * 128) = b;
    }
  }

  // GeM reduce over the 8 w4-lanes
  {
    float u0 = g0, u1 = g1;
    u0 += __shfl_xor(u0, 1, 8); u1 += __shfl_xor(u1, 1, 8);
    u0 += __shfl_xor(u0, 2, 8); u1 += __shfl_xor(u1, 2, 8);
    u0 += __shfl_xor(u0, 4, 8); u1 += __shfl_xor(u1, 4, 8);
    if (w4 == 0) {
      atomicAdd(&gbuf[n * D_ + d0 + dg * 2    ], u0);
      atomicAdd(&gbuf[n * D_ + d0 + dg * 2 + 1], u1);
    }
  }
}

// ---- K3: proj_w fp32 -> bf16, fragment-packed: packB[wq][kt][nf][lane][8] ----
__global__ __launch_bounds__(256) void k_wconv(const float* __restrict__ w, u16* __restrict__ packB) {
  const int i = blockIdx.x * 256 + threadIdx.x;   // 0..131071
  const int lane = i & 63, nf = (i >> 6) & 3, kt = (i >> 8) & 63, wq = i >> 14;  // wq 0..7
  const int r15 = lane & 15, hi = lane >> 4;
  const int f = wq * 64 + nf * 16 + r15;
  const int k = kt * 32 + hi * 8;
  const float* src = w + (size_t)f * D_ + k;
  float4 v0 = *(const float4*)(src);
  float4 v1 = *(const float4*)(src + 4);
  u32 r[4] = { f2bf2(v0.x, v0.y), f2bf2(v0.z, v0.w),
               f2bf2(v1.x, v1.y), f2bf2(v1.z, v1.w) };
  *(uint4*)(packB + (size_t)i * 8) = *(const uint4*)r;
}

// ---- K4: GEMM [64 hw] x [512 f] x [K 2048] (r8/r13 form, best measured) ----
__global__ __launch_bounds__(512) void k_gemm(const u16* __restrict__ packA,
    const u16* __restrict__ packB, const float* __restrict__ bias,
    float* __restrict__ outL) {
  const int n  = blockIdx.x >> 4;
  const int mtl = blockIdx.x & 15;
  const int mt = blockIdx.x;            // global 64-row tile index
  const int hw0 = mtl * 64;
  const int t = threadIdx.x;
  const int lane = t & 63, wv = t >> 6;
  const int r15 = lane & 15, hi = lane >> 4;

  __shared__ __align__(16) float smem_f[128 * 68];   // 34.8 KB; A bufs alias first 16 KB
  __shared__ float s_sq[8][64];
  __shared__ float s_rn[64];

  f32x4 acc[4][4];
  #pragma unroll
  for (int a = 0; a < 4; ++a)
    #pragma unroll
    for (int b = 0; b < 4; ++b) acc[a][b] = (f32x4){0.f, 0.f, 0.f, 0.f};

  const u16* asrc = packA + ((size_t)(mt * 64) * 4 + (wv & 3)) * 512 + lane * 8;
  const u16* bbase = packB + (size_t)wv * 131072 + lane * 8;

#define STAGE_A(KT) GLD_LDS16(asrc + (size_t)(KT) * 2048, \
    (char*)smem_f + ((KT) & 3) * 4096 + (wv & 3) * 1024)

  STAGE_A(0);
  STAGE_A(1);
  bf16x8 bc[4], bn[4];
  #pragma unroll
  for (int nf = 0; nf < 4; ++nf) bc[nf] = *(const bf16x8*)(bbase + nf * 512);

  for (int kt = 0; kt < 64; ++kt) {
    if (kt + 2 < 64) STAGE_A(kt + 2);
    if (kt + 1 < 64) {
      #pragma unroll
      for (int nf = 0; nf < 4; ++nf)
        bn[nf] = *(const bf16x8*)(bbase + ((kt + 1) * 4 + nf) * 512);
    }
    __builtin_amdgcn_sched_barrier(0);
    if (kt < 62) {
      asm volatile("s_waitcnt vmcnt(5)" ::: "memory");   // A(kt)+B(kt) retired
    } else if (kt == 62) {
      asm volatile("s_waitcnt vmcnt(4)" ::: "memory");
    } else {
      asm volatile("s_waitcnt vmcnt(0)" ::: "memory");
    }
    __builtin_amdgcn_sched_barrier(0);
    __builtin_amdgcn_s_barrier();                         // A tile kt visible
    __builtin_amdgcn_sched_barrier(0);

    const u16* sA = (const u16*)((const char*)smem_f + (kt & 3) * 4096);
    bf16x8 af[4];
    #pragma unroll
    for (int mf = 0; mf < 4; ++mf)
      af[mf] = *(const bf16x8*)(sA + mf * 512 + lane * 8);
    #pragma unroll
    for (int mf = 0; mf < 4; ++mf)
      #pragma unroll
      for (int nf = 0; nf < 4; ++nf)
        acc[mf][nf] = __builtin_amdgcn_mfma_f32_16x16x32_bf16(af[mf], bc[nf], acc[mf][nf], 0, 0, 0);
    #pragma unroll
    for (int nf = 0; nf < 4; ++nf) bc[nf] = bn[nf];
  }
#undef STAGE_A

  // epilogue: bias, per-row (hw) l2 norm over all 512 f, transposed store
  float badd[4];
  #pragma unroll
  for (int nf = 0; nf < 4; ++nf) badd[nf] = bias[wv * 64 + nf * 16 + r15];
  #pragma unroll
  for (int mf = 0; mf < 4; ++mf)
    #pragma unroll
    for (int nf = 0; nf < 4; ++nf)
      #pragma unroll
      for (int j = 0; j < 4; ++j) acc[mf][nf][j] += badd[nf];

  #pragma unroll
  for (int mf = 0; mf < 4; ++mf)
    #pragma unroll
    for (int j = 0; j < 4; ++j) {
      float s = 0.f;
      #pragma unroll
      for (int nf = 0; nf < 4; ++nf) { float v = acc[mf][nf][j]; s += v * v; }
      s += __shfl_xor(s, 1); s += __shfl_xor(s, 2); s += __shfl_xor(s, 4); s += __shfl_xor(s, 8);
      if ((lane & 15) == 0) s_sq[wv][mf * 16 + hi * 4 + j] = s;
    }
  __syncthreads();
  if (t < 64) {
    float s = 0.f;
    #pragma unroll
    for (int w8 = 0; w8 < 8; ++w8) s += s_sq[w8][t];
    s_rn[t] = 1.0f / fmaxf(sqrtf(s), 1e-12f);
  }
  __syncthreads();

  float* ct = smem_f;   // [128 f-rows][68] fp32
  for (int nf = 0; nf < 4; ++nf) {
    const int fi = wv * 16 + r15;
    #pragma unroll
    for (int mf = 0; mf < 4; ++mf)
      #pragma unroll
      for (int j = 0; j < 4; ++j) {
        int m = mf * 16 + hi * 4 + j;
        ct[fi * 68 + m] = acc[mf][nf][j] * s_rn[m];
      }
    __syncthreads();
    {
      int fr = t >> 2, mq = t & 3;
      int f = (fr >> 4) * 64 + nf * 16 + (fr & 15);
      float* dst = outL + ((size_t)(n * F_ + f)) * HW_ + hw0 + mq * 16;
      const float* srcp = ct + fr * 68 + mq * 16;
      float4 a0 = *(const float4*)(srcp);
      float4 a1 = *(const float4*)(srcp + 4);
      float4 a2 = *(const float4*)(srcp + 8);
      float4 a3 = *(const float4*)(srcp + 12);
      *(float4*)(dst) = a0; *(float4*)(dst + 4) = a1;
      *(float4*)(dst + 8) = a2; *(float4*)(dst + 12) = a3;
    }
    __syncthreads();
  }
}

// ---- K5: GeM finalize: gg = (gbuf/1024)^(1/p) ----
__global__ __launch_bounds__(256) void k_gem_fin(const float* __restrict__ gbuf,
    const float* __restrict__ pvec, float* __restrict__ gg) {
  int i = blockIdx.x * 256 + threadIdx.x;
  float p = pvec[0];
  float m = gbuf[i] * (1.0f / 1024.0f);
  gg[i] = (p == 3.0f) ? cbrtf(m) : powf(m, 1.0f / p);
}

// ---- K6: gproj[n][f] = dot(gg[n], W[f]) + b[f] ----
__global__ __launch_bounds__(256) void k_gproj(const float* __restrict__ w,
    const float* __restrict__ bias, const float* __restrict__ gg,
    float* __restrict__ gproj) {
  const int f = blockIdx.x;
  const int t = threadIdx.x;
  float wreg[8];
  #pragma unroll
  for (int j = 0; j < 8; ++j) wreg[j] = w[(size_t)f * D_ + t + j * 256];
  __shared__ float red[4];
  const int lane = t & 63, wv = t >> 6;
  for (int n = 0; n < N_; ++n) {
    float s = 0.f;
    #pragma unroll
    for (int j = 0; j < 8; ++j) s += wreg[j] * gg[n * D_ + t + j * 256];
    #pragma unroll
    for (int off = 32; off >= 1; off >>= 1) s += __shfl_down(s, off);
    if (lane == 0) red[wv] = s;
    __syncthreads();
    if (t == 0) gproj[n * F_ + f] = red[0] + red[1] + red[2] + red[3] + bias[f];
    __syncthreads();
  }
}

// ---- K7: l2norm g rows -> d_out[0:8192] ----
__global__ __launch_bounds__(512) void k_gnorm(const float* __restrict__ gproj, float* __restrict__ outg) {
  const int n = blockIdx.x;
  const int t = threadIdx.x;
  float v = gproj[n * F_ + t];
  float s = v * v;
  const int lane = t & 63, wv = t >> 6;
  #pragma unroll
  for (int off = 32; off >= 1; off >>= 1) s += __shfl_down(s, off);
  __shared__ float red[8];
  __shared__ float rtot;
  if (lane == 0) red[wv] = s;
  __syncthreads();
  if (t == 0) {
    float a = 0.f;
    #pragma unroll
    for (int i = 0; i < 8; ++i) a += red[i];
    rtot = 1.0f / fmaxf(sqrtf(a), 1e-12f);
  }
  __syncthreads();
  outg[n * F_ + t] = v * rtot;
}

extern "C" void kernel_launch(void* const* d_in, const int* in_sizes, int n_in,
                              void* d_out, int out_size, void* d_ws, size_t ws_size,
                              hipStream_t stream) {
  const float* x  = (const float*)d_in[0];
  const float* pw = (const float*)d_in[1];
  const float* pb = (const float*)d_in[2];
  const float* pv = (const float*)d_in[3];
  float* out = (float*)d_out;

  char* ws = (char*)d_ws;
  float* sumsq = (float*)ws;                                   // 64 KB
  float* gbuf  = (float*)(ws + 65536);                         // 128 KB
  float* gg    = (float*)(ws + 65536 + 131072);                // 128 KB
  float* gproj = (float*)(ws + 65536 + 2 * 131072);            // 32 KB
  u16*   packB = (u16*)(ws + 65536 + 2 * 131072 + 32768);      // 2 MiB
  u16*   packA = (u16*)(ws + 4u * 1024u * 1024u);              // 64 MiB

  k_zero<<<dim3(48), dim3(256), 0, stream>>>(sumsq);           // sumsq + gbuf
  k_sumsq<<<dim3(16, 32), dim3(256), 0, stream>>>(x, sumsq);
  k_wconv<<<dim3(512), dim3(256), 0, stream>>>(pw, packB);
  k_box2<<<dim3(16, 8, 32), dim3(256), 0, stream>>>(x, sumsq, pv, gbuf, packA);
  k_gem_fin<<<dim3(128), dim3(256), 0, stream>>>(gbuf, pv, gg);
  k_gproj<<<dim3(512), dim3(256), 0, stream>>>(pw, pb, gg, gproj);
  k_gnorm<<<dim3(16), dim3(512), 0, stream>>>(gproj, out);
  k_gemm<<<dim3(256), dim3(512), 0, stream>>>(packA, packB, pb, out + N_ * F_);
}

// Round 17
// 141.018 us; speedup vs baseline: 1.0226x; 1.0004x over previous
//
#include <hip/hip_runtime.h>
#include <hip/hip_bf16.h>

#define N_ 16
#define D_ 2048
#define H_ 32
#define W_ 32
#define HW_ 1024
#define F_ 512

typedef unsigned short u16;
typedef unsigned int u32;
typedef __attribute__((ext_vector_type(8))) short bf16x8;
typedef __attribute__((ext_vector_type(4))) float f32x4;

__device__ __forceinline__ u16 f2bf(float f) {
  __hip_bfloat16 h = __float2bfloat16(f);
  union { __hip_bfloat16 h; u16 u; } c; c.h = h;
  return c.u;
}

// ---- K0: zero sumsq+gbuf (192 KB contiguous) ----
__global__ __launch_bounds__(256) void k_zero(float* __restrict__ p) {
  int i = blockIdx.x * 256 + threadIdx.x;
  ((float4*)p)[i] = (float4){0.f, 0.f, 0.f, 0.f};
}

// ---- K1: sum of squares over channel dim -> sumsq[n][hw] (atomic partials) ----
__global__ __launch_bounds__(256) void k_sumsq(const float* __restrict__ x, float* __restrict__ sumsq) {
  const int n = blockIdx.x;        // 16
  const int dc = blockIdx.y;       // 32 chunks x 64 d
  const int t = threadIdx.x;
  const float* xp = x + ((size_t)n * D_ + (size_t)dc * 64) * HW_;
  float s0 = 0.f, s1 = 0.f, s2 = 0.f, s3 = 0.f;
  for (int d = 0; d < 64; ++d) {
    const float* row = xp + (size_t)d * HW_;
    float v0 = row[t], v1 = row[t + 256], v2 = row[t + 512], v3 = row[t + 768];
    s0 += v0 * v0; s1 += v1 * v1; s2 += v2 * v2; s3 += v3 * v3;
  }
  atomicAdd(&sumsq[n * HW_ + t      ], s0);
  atomicAdd(&sumsq[n * HW_ + t + 256], s1);
  atomicAdd(&sumsq[n * HW_ + t + 512], s2);
  atomicAdd(&sumsq[n * HW_ + t + 768], s3);
}

// ---- K3: proj_w fp32 -> bf16, fragment-packed: packB[wq][kt][nf][lane][8] ----
__global__ __launch_bounds__(256) void k_wconv(const float* __restrict__ w, u16* __restrict__ packB) {
  const int i = blockIdx.x * 256 + threadIdx.x;   // 0..131071
  const int lane = i & 63, nf = (i >> 6) & 3, kt = (i >> 8) & 63, wq = i >> 14;  // wq 0..7
  const int r15 = lane & 15, hi = lane >> 4;
  const int f = wq * 64 + nf * 16 + r15;
  const int k = kt * 32 + hi * 8;
  const float* src = w + (size_t)f * D_ + k;
  float4 v0 = *(const float4*)(src);
  float4 v1 = *(const float4*)(src + 4);
  u16 r[8] = { f2bf(v0.x), f2bf(v0.y), f2bf(v0.z), f2bf(v0.w),
               f2bf(v1.x), f2bf(v1.y), f2bf(v1.z), f2bf(v1.w) };
  *(uint4*)(packB + (size_t)i * 8) = *(const uint4*)r;
}

// ---- K4: FUSED box + GEMM ----
// 256 blocks (mt), 512 thr. Block owns hw rows hw0..hw0+63 = h rows hA, hA+1.
// Per K-step kt (32 d's): p1 load x halo rows (hA-1..hA+2) x 32d from L3,
// normalize, GeM partial, horizontal 3-tap -> hs LDS; p2 vertical 3-tap ->
// bf16 A-fragment tile in LDS; p3 ds_read frags + MFMA with B from regs.
// No global_load_lds: all loads register-tracked (compiler-inserted waits).
// 2 barriers/step; hs + Af single-buffered (safety: p2(kt+1) writes only after
// bar1(kt+1), which requires all waves past p3(kt)).
__global__ __launch_bounds__(512) void k_boxgemm(const float* __restrict__ x,
    const float* __restrict__ sumsq, const float* __restrict__ pvec,
    const u16* __restrict__ packB, const float* __restrict__ bias,
    float* __restrict__ gbuf, float* __restrict__ outL) {
  const int mt = blockIdx.x;            // 0..255
  const int n  = mt >> 4;
  const int hA = (mt & 15) * 2;
  const int hw0 = (mt & 15) * 64;
  const int t = threadIdx.x;
  const int lane = t & 63, wv = t >> 6;
  const int r15 = lane & 15, hi = lane >> 4;
  const int hp2 = t >> 8;               // 0/1 (uniform per wave)
  const int dd = (t & 255) >> 3;        // 0..31
  const int w4 = t & 7, wq = w4 * 4;
  const float p = pvec[0];
  const bool p3c = (p == 3.0f);

  __shared__ __align__(16) float smem[128 * 68];   // 34.8 KB, phase-aliased
  float* hs = smem;                      // [4][32][36] f32 = 4608 floats
  u16*   Af = (u16*)(smem + 4608);       // 2048 u16 = 1024 floats
  float* rnl = smem + 4608 + 1024;       // [4][32] f32
  __shared__ float s_sq[8][64];
  __shared__ float s_rn[64];

  // inverse norms for the 4 halo rows
  if (t < 128) {
    int jj = t >> 5, w = t & 31;
    int hp = hA - 1 + jj;
    float r = 0.f;
    if (hp >= 0 && hp < H_) r = 1.0f / fmaxf(sqrtf(sumsq[n * HW_ + hp * W_ + w]), 1e-12f);
    rnl[jj * 32 + w] = r;
  }
  __syncthreads();

  f32x4 acc[4][4];
  #pragma unroll
  for (int a = 0; a < 4; ++a)
    #pragma unroll
    for (int b = 0; b < 4; ++b) acc[a][b] = (f32x4){0.f, 0.f, 0.f, 0.f};

  // x slot pointers: slot0 row hA-1+hp2, slot1 row hA+1+hp2
  const int hpa0 = hA - 1 + hp2;
  const int hpa1 = hA + 1 + hp2;
  const bool val0 = (hpa0 >= 0);        // upper bound always ok (<= hA+1 <= 31)
  const bool val1 = (hpa1 < H_);
  const float* xb0 = x + ((size_t)(n * D_ + dd) * HW_ + (val0 ? hpa0 : 0) * W_ + wq);
  const float* xb1 = x + ((size_t)(n * D_ + dd) * HW_ + (val1 ? hpa1 : 0) * W_ + wq);
  const int hsoff0 = hp2 * 1152 + dd * 36 + wq;        // hprel = hp2
  const int hsoff1 = (hp2 + 2) * 1152 + dd * 36 + wq;  // hprel = hp2+2
  const float4 zero4 = {0.f, 0.f, 0.f, 0.f};

  // B fragments (contiguous 1KB each; wave owns f-quad wv)
  const u16* bbase = packB + (size_t)wv * 131072 + lane * 8;

  float4 xa0 = val0 ? *(const float4*)(xb0) : zero4;
  float4 xa1 = val1 ? *(const float4*)(xb1) : zero4;
  bf16x8 bc[4], bn[4];
  #pragma unroll
  for (int nf = 0; nf < 4; ++nf) bc[nf] = *(const bf16x8*)(bbase + nf * 512);

  for (int kt = 0; kt < 64; ++kt) {
    float4 xn0, xn1;
    if (kt < 63) {
      const size_t xoff = (size_t)(kt + 1) * 32 * HW_;
      xn0 = val0 ? *(const float4*)(xb0 + xoff) : zero4;
      xn1 = val1 ? *(const float4*)(xb1 + xoff) : zero4;
      #pragma unroll
      for (int nf = 0; nf < 4; ++nf)
        bn[nf] = *(const bf16x8*)(bbase + ((size_t)(kt + 1) * 4 + nf) * 512);
    }

    // ---- p1: normalize + GeM + horizontal 3-tap -> hs ----
    float4 rr0 = *(const float4*)(rnl + hp2 * 32 + wq);
    float4 rr1 = *(const float4*)(rnl + (hp2 + 2) * 32 + wq);
    float4 v0, v1;
    v0.x = xa0.x * rr0.x; v0.y = xa0.y * rr0.y; v0.z = xa0.z * rr0.z; v0.w = xa0.w * rr0.w;
    v1.x = xa1.x * rr1.x; v1.y = xa1.y * rr1.y; v1.z = xa1.z * rr1.z; v1.w = xa1.w * rr1.w;
    {
      // GeM row: hp2==1 -> slot0 (row hA); hp2==0 -> slot1 (row hA+1)
      float4 pk = hp2 ? v0 : v1;
      float cx = fmaxf(pk.x, 1e-6f), cy = fmaxf(pk.y, 1e-6f);
      float cz = fmaxf(pk.z, 1e-6f), cw = fmaxf(pk.w, 1e-6f);
      float g;
      if (p3c) g = cx * cx * cx + cy * cy * cy + cz * cz * cz + cw * cw * cw;
      else     g = __powf(cx, p) + __powf(cy, p) + __powf(cz, p) + __powf(cw, p);
      g += __shfl_xor(g, 1, 8);
      g += __shfl_xor(g, 2, 8);
      g += __shfl_xor(g, 4, 8);
      if (w4 == 0) atomicAdd(&gbuf[n * D_ + kt * 32 + dd], g);
    }
    {
      float lf = __shfl_up(v0.w, 1, 8), rf = __shfl_down(v0.x, 1, 8);
      if (w4 == 0) lf = 0.f;
      if (w4 == 7) rf = 0.f;
      float4 h;
      h.x = lf + v0.x + v0.y;  h.y = v0.x + v0.y + v0.z;
      h.z = v0.y + v0.z + v0.w; h.w = v0.z + v0.w + rf;
      *(float4*)(hs + hsoff0) = h;
    }
    {
      float lf = __shfl_up(v1.w, 1, 8), rf = __shfl_down(v1.x, 1, 8);
      if (w4 == 0) lf = 0.f;
      if (w4 == 7) rf = 0.f;
      float4 h;
      h.x = lf + v1.x + v1.y;  h.y = v1.x + v1.y + v1.z;
      h.z = v1.y + v1.z + v1.w; h.w = v1.z + v1.w + rf;
      *(float4*)(hs + hsoff1) = h;
    }
    __syncthreads();

    // ---- p2: vertical 3-tap -> bf16 A-fragment tile ----
    {
      const float* hb = hs + hp2 * 1152 + dd * 36 + wq;
      float4 h0 = *(const float4*)(hb);
      float4 h1 = *(const float4*)(hb + 1152);
      float4 h2 = *(const float4*)(hb + 2304);
      float o[4] = { h0.x + h1.x + h2.x, h0.y + h1.y + h2.y,
                     h0.z + h1.z + h2.z, h0.w + h1.w + h2.w };
      const int hii = dd >> 3, jj = dd & 7;
      #pragma unroll
      for (int i = 0; i < 4; ++i) {
        int r = hp2 * 32 + wq + i;
        Af[(r >> 4) * 512 + hii * 128 + (r & 15) * 8 + jj] = f2bf(o[i]);
      }
    }
    __syncthreads();

    // ---- p3: MFMA ----
    bf16x8 af[4];
    #pragma unroll
    for (int mf = 0; mf < 4; ++mf)
      af[mf] = *(const bf16x8*)(Af + mf * 512 + lane * 8);
    #pragma unroll
    for (int mf = 0; mf < 4; ++mf)
      #pragma unroll
      for (int nf = 0; nf < 4; ++nf)
        acc[mf][nf] = __builtin_amdgcn_mfma_f32_16x16x32_bf16(af[mf], bc[nf], acc[mf][nf], 0, 0, 0);

    xa0 = xn0; xa1 = xn1;
    #pragma unroll
    for (int nf = 0; nf < 4; ++nf) bc[nf] = bn[nf];
  }

  // ---- epilogue: bias, per-row (hw) l2 norm over all 512 f, transposed store ----
  __syncthreads();
  float badd[4];
  #pragma unroll
  for (int nf = 0; nf < 4; ++nf) badd[nf] = bias[wv * 64 + nf * 16 + r15];
  #pragma unroll
  for (int mf = 0; mf < 4; ++mf)
    #pragma unroll
    for (int nf = 0; nf < 4; ++nf)
      #pragma unroll
      for (int j = 0; j < 4; ++j) acc[mf][nf][j] += badd[nf];

  #pragma unroll
  for (int mf = 0; mf < 4; ++mf)
    #pragma unroll
    for (int j = 0; j < 4; ++j) {
      float s = 0.f;
      #pragma unroll
      for (int nf = 0; nf < 4; ++nf) { float v = acc[mf][nf][j]; s += v * v; }
      s += __shfl_xor(s, 1); s += __shfl_xor(s, 2); s += __shfl_xor(s, 4); s += __shfl_xor(s, 8);
      if ((lane & 15) == 0) s_sq[wv][mf * 16 + hi * 4 + j] = s;
    }
  __syncthreads();
  if (t < 64) {
    float s = 0.f;
    #pragma unroll
    for (int w8 = 0; w8 < 8; ++w8) s += s_sq[w8][t];
    s_rn[t] = 1.0f / fmaxf(sqrtf(s), 1e-12f);
  }
  __syncthreads();

  float* ct = smem;   // [128 f-rows][68] fp32
  for (int nf = 0; nf < 4; ++nf) {
    const int fi = wv * 16 + r15;
    #pragma unroll
    for (int mf = 0; mf < 4; ++mf)
      #pragma unroll
      for (int j = 0; j < 4; ++j) {
        int m = mf * 16 + hi * 4 + j;
        ct[fi * 68 + m] = acc[mf][nf][j] * s_rn[m];
      }
    __syncthreads();
    {
      int fr = t >> 2, mq = t & 3;
      int f = (fr >> 4) * 64 + nf * 16 + (fr & 15);
      float* dst = outL + ((size_t)(n * F_ + f)) * HW_ + hw0 + mq * 16;
      const float* srcp = ct + fr * 68 + mq * 16;
      float4 a0 = *(const float4*)(srcp);
      float4 a1 = *(const float4*)(srcp + 4);
      float4 a2 = *(const float4*)(srcp + 8);
      float4 a3 = *(const float4*)(srcp + 12);
      *(float4*)(dst) = a0; *(float4*)(dst + 4) = a1;
      *(float4*)(dst + 8) = a2; *(float4*)(dst + 12) = a3;
    }
    __syncthreads();
  }
}

// ---- K5: GeM finalize: gg = (gbuf/1024)^(1/p) ----
__global__ __launch_bounds__(256) void k_gem_fin(const float* __restrict__ gbuf,
    const float* __restrict__ pvec, float* __restrict__ gg) {
  int i = blockIdx.x * 256 + threadIdx.x;
  float p = pvec[0];
  float m = gbuf[i] * (1.0f / 1024.0f);
  gg[i] = (p == 3.0f) ? cbrtf(m) : powf(m, 1.0f / p);
}

// ---- K6: gproj[n][f] = dot(gg[n], W[f]) + b[f] ----
__global__ __launch_bounds__(256) void k_gproj(const float* __restrict__ w,
    const float* __restrict__ bias, const float* __restrict__ gg,
    float* __restrict__ gproj) {
  const int f = blockIdx.x;
  const int t = threadIdx.x;
  float wreg[8];
  #pragma unroll
  for (int j = 0; j < 8; ++j) wreg[j] = w[(size_t)f * D_ + t + j * 256];
  __shared__ float red[4];
  const int lane = t & 63, wv = t >> 6;
  for (int n = 0; n < N_; ++n) {
    float s = 0.f;
    #pragma unroll
    for (int j = 0; j < 8; ++j) s += wreg[j] * gg[n * D_ + t + j * 256];
    #pragma unroll
    for (int off = 32; off >= 1; off >>= 1) s += __shfl_down(s, off);
    if (lane == 0) red[wv] = s;
    __syncthreads();
    if (t == 0) gproj[n * F_ + f] = red[0] + red[1] + red[2] + red[3] + bias[f];
    __syncthreads();
  }
}

// ---- K7: l2norm g rows -> d_out[0:8192] ----
__global__ __launch_bounds__(512) void k_gnorm(const float* __restrict__ gproj, float* __restrict__ outg) {
  const int n = blockIdx.x;
  const int t = threadIdx.x;
  float v = gproj[n * F_ + t];
  float s = v * v;
  const int lane = t & 63, wv = t >> 6;
  #pragma unroll
  for (int off = 32; off >= 1; off >>= 1) s += __shfl_down(s, off);
  __shared__ float red[8];
  __shared__ float rtot;
  if (lane == 0) red[wv] = s;
  __syncthreads();
  if (t == 0) {
    float a = 0.f;
    #pragma unroll
    for (int i = 0; i < 8; ++i) a += red[i];
    rtot = 1.0f / fmaxf(sqrtf(a), 1e-12f);
  }
  __syncthreads();
  outg[n * F_ + t] = v * rtot;
}

extern "C" void kernel_launch(void* const* d_in, const int* in_sizes, int n_in,
                              void* d_out, int out_size, void* d_ws, size_t ws_size,
                              hipStream_t stream) {
  const float* x  = (const float*)d_in[0];
  const float* pw = (const float*)d_in[1];
  const float* pb = (const float*)d_in[2];
  const float* pv = (const float*)d_in[3];
  float* out = (float*)d_out;

  char* ws = (char*)d_ws;
  float* sumsq = (float*)ws;                                   // 64 KB
  float* gbuf  = (float*)(ws + 65536);                         // 128 KB
  float* gg    = (float*)(ws + 65536 + 131072);                // 128 KB
  float* gproj = (float*)(ws + 65536 + 2 * 131072);            // 32 KB
  u16*   packB = (u16*)(ws + 65536 + 2 * 131072 + 32768);      // 2 MiB

  k_zero<<<dim3(48), dim3(256), 0, stream>>>(sumsq);           // sumsq + gbuf
  k_sumsq<<<dim3(16, 32), dim3(256), 0, stream>>>(x, sumsq);
  k_wconv<<<dim3(512), dim3(256), 0, stream>>>(pw, packB);
  k_boxgemm<<<dim3(256), dim3(512), 0, stream>>>(x, sumsq, pv, packB, pb, gbuf, out + N_ * F_);
  k_gem_fin<<<dim3(128), dim3(256), 0, stream>>>(gbuf, pv, gg);
  k_gproj<<<dim3(512), dim3(256), 0, stream>>>(pw, pb, gg, gproj);
  k_gnorm<<<dim3(16), dim3(512), 0, stream>>>(gproj, out);
}